// Round 12
// baseline (198.256 us; speedup 1.0000x reference)
//
#include <hip/hip_runtime.h>

typedef unsigned long long u64;
typedef int i32x4 __attribute__((ext_vector_type(4)));

#define HW    3136      // 56*56 ; 3136 % 32 == 0 -> tiles never straddle images
#define CIN   256
#define CMID  768
#define EPSV  1e-5

// ---------------------------------------------------------------------------
// prep: weights -> i8 sign matrices (-1/0/+1); BN folded to (inv, c) f32 pairs:
//   y_bn = y*inv + c,  inv = g*rsqrt(v+eps), c = b - m*inv
// ---------------------------------------------------------------------------
__global__ __launch_bounds__(64) void prep_kernel(
    const float* __restrict__ w1, const float* __restrict__ w2,
    const float* __restrict__ g1, const float* __restrict__ b1,
    const float* __restrict__ m1, const float* __restrict__ v1,
    const float* __restrict__ g2, const float* __restrict__ b2,
    const float* __restrict__ m2, const float* __restrict__ v2,
    char* __restrict__ w1b, char* __restrict__ w2b,
    float2* __restrict__ ic1, float2* __restrict__ ic2)
{
  int blk = blockIdx.x, lane = threadIdx.x;
  if (blk < 1536) {                       // 2 x 196608 weight elements, 4/thread
    const float* src = (blk < 768) ? w1 : w2;
    char*        dst = (blk < 768) ? w1b : w2b;
    int idx  = ((blk < 768) ? blk : blk - 768) * 64 + lane;
    int base = idx * 4;
    unsigned d = 0;
    #pragma unroll
    for (int j = 0; j < 4; ++j) {
      float v = src[base + j];
      unsigned s = (v < 0.f) ? 0xFFu : (v > 0.f ? 1u : 0u);
      d |= s << (8 * j);
    }
    *(unsigned*)(dst + base) = d;
  } else {
    int i = (blk - 1536) * 64 + lane;     // 1024 BN entries
    if (i < CMID) {
      double inv = (double)g1[i] / sqrt((double)v1[i] + EPSV);
      float2 o; o.x = (float)inv;
      o.y = (float)((double)b1[i] - (double)m1[i] * inv);
      ic1[i] = o;
    } else {
      int j = i - CMID;
      double inv = (double)g2[j] / sqrt((double)v2[j] + EPSV);
      float2 o; o.x = (float)inv;
      o.y = (float)((double)b2[j] - (double)m2[j] * inv);
      ic2[j] = o;
    }
  }
}

// ---------------------------------------------------------------------------
// main: 3136 blocks x 256 thr (4 waves), 32-pixel tile, both layers on MFMA.
// Identical structure to the R7 kernel except tile 64->32:
// LDS 32.25 KB -> 4 blocks/CU (16 waves) vs R7's 2 blocks (8 waves).
// sBx/sY layouts [px][k] i8, XOR swizzle ^(px&15)<<4 on 16B slots.
// L1: wave w rows [192w,+192) in 4 chunks of 48 (3 M-tiles x 2 N-tiles),
//     B-frags (whole K=256) hoisted (8 regs x4). A-frags from global (L2$).
// L2: wave w rows [64w,+64), K=768 from sY, 2 N-tiles.
// sign(0)=0 handled natively by the 0 byte in i8 MFMA.
// ---------------------------------------------------------------------------
__global__ __launch_bounds__(256, 4) void bnn_kernel(
    const float* __restrict__ x,
    const char* __restrict__ w1b, const char* __restrict__ w2b,
    const float2* __restrict__ ic1, const float2* __restrict__ ic2,
    float* __restrict__ out)
{
  __shared__ __align__(16) char sBx[32 * 256];   // 8 KB
  __shared__ __align__(16) char sY[32 * 768];    // 24 KB  (total 32.25 KB)

  int t    = threadIdx.x;
  int w    = t >> 6;
  int lane = t & 63;
  int l15  = lane & 15;
  int g4   = lane >> 4;
  int swz  = l15 << 4;

  int px0 = blockIdx.x * 32;           // 3136*32 == 100352 exactly
  int b   = px0 / HW;
  int hw0 = px0 - b * HW;
  const float* xb = x   + (size_t)b * (CIN * HW) + hw0;
  float*       ob = out + (size_t)b * (CIN * HW) + hw0;

  // ---- pack: thread packs px = t&31, chans [32h, 32h+32), h = t>>5 ----
  {
    int p = t & 31, h = t >> 5;
    const float* xp = xb + p + (size_t)(h << 5) * HW;
    int rowbase = p * 256 + (h << 5);
    int pswz    = (p & 15) << 4;
    #pragma unroll
    for (int j = 0; j < 2; ++j) {      // 2 x b128 (16 chans each)
      unsigned d[4];
      #pragma unroll
      for (int q = 0; q < 4; ++q) {
        unsigned dv = 0;
        #pragma unroll
        for (int bb = 0; bb < 4; ++bb) {
          int c = j * 16 + q * 4 + bb;
          unsigned u = __float_as_uint(xp[(size_t)c * HW]);
          unsigned s = ((u + u) == 0u) ? 0u : (((int)u < 0) ? 0xFFu : 1u);
          dv |= s << (8 * bb);
        }
        d[q] = dv;
      }
      i32x4 v; v.x = (int)d[0]; v.y = (int)d[1]; v.z = (int)d[2]; v.w = (int)d[3];
      *(i32x4*)&sBx[(rowbase + j * 16) ^ pswz] = v;
    }
  }
  __syncthreads();

  // ---- hoist B-fragments (whole K=256, 2 N-tiles) ----
  i32x4 bfa[4][2];                     // [ks][n]
  #pragma unroll
  for (int ks = 0; ks < 4; ++ks) {
    int k0 = ks * 64 + g4 * 16;
    #pragma unroll
    for (int n = 0; n < 2; ++n)
      bfa[ks][n] = *(const i32x4*)&sBx[((n * 16 + l15) * 256 + k0) ^ swz];
  }

  // ---- layer 1: 4 chunks of 48 rows ----
  int wrow = w * 192;
  #pragma unroll 1
  for (int ch = 0; ch < 4; ++ch) {
    int rbase = wrow + ch * 48;
    i32x4 acc[3][2];
    #pragma unroll
    for (int m = 0; m < 3; ++m)
      #pragma unroll
      for (int n = 0; n < 2; ++n) acc[m][n] = (i32x4)0;

    #pragma unroll
    for (int ks = 0; ks < 4; ++ks) {
      int k0 = ks * 64 + g4 * 16;
      i32x4 af[3];
      #pragma unroll
      for (int m = 0; m < 3; ++m)
        af[m] = *(const i32x4*)&w1b[(size_t)(rbase + m * 16 + l15) * 256 + k0];
      #pragma unroll
      for (int m = 0; m < 3; ++m)
        #pragma unroll
        for (int n = 0; n < 2; ++n)
          acc[m][n] = __builtin_amdgcn_mfma_i32_16x16x64_i8(
              af[m], bfa[ks][n], acc[m][n], 0, 0, 0);
    }

    // epilogue: BN-threshold -> i8 sign bytes into sY
    #pragma unroll
    for (int m = 0; m < 3; ++m) {
      int r0 = rbase + m * 16 + g4 * 4;
      float2 c0 = ic1[r0], c1 = ic1[r0 + 1], c2 = ic1[r0 + 2], c3 = ic1[r0 + 3];
      #pragma unroll
      for (int n = 0; n < 2; ++n) {
        int px = n * 16 + l15;
        float y0 = fmaf((float)acc[m][n].x, c0.x, c0.y);
        float y1 = fmaf((float)acc[m][n].y, c1.x, c1.y);
        float y2 = fmaf((float)acc[m][n].z, c2.x, c2.y);
        float y3 = fmaf((float)acc[m][n].w, c3.x, c3.y);
        unsigned dv =
            (unsigned)(y0 < 0.f ? 0xFFu : (y0 > 0.f ? 1u : 0u))
          | ((unsigned)(y1 < 0.f ? 0xFFu : (y1 > 0.f ? 1u : 0u)) << 8)
          | ((unsigned)(y2 < 0.f ? 0xFFu : (y2 > 0.f ? 1u : 0u)) << 16)
          | ((unsigned)(y3 < 0.f ? 0xFFu : (y3 > 0.f ? 1u : 0u)) << 24);
        *(unsigned*)&sY[(px * 768 + r0) ^ swz] = dv;
      }
    }
  }
  __syncthreads();

  // ---- layer 2: wave rows [64w,+64), K=768, BN + residual + store ----
  {
    int rbase = w << 6;
    i32x4 acc[4][2];
    #pragma unroll
    for (int m = 0; m < 4; ++m)
      #pragma unroll
      for (int n = 0; n < 2; ++n) acc[m][n] = (i32x4)0;

    #pragma unroll 4
    for (int ks = 0; ks < 12; ++ks) {
      int k0 = ks * 64 + g4 * 16;
      i32x4 bf[2];
      #pragma unroll
      for (int n = 0; n < 2; ++n)
        bf[n] = *(const i32x4*)&sY[((n * 16 + l15) * 768 + k0) ^ swz];
      i32x4 af[4];
      #pragma unroll
      for (int m = 0; m < 4; ++m)
        af[m] = *(const i32x4*)&w2b[(size_t)(rbase + m * 16 + l15) * 768 + k0];
      #pragma unroll
      for (int m = 0; m < 4; ++m)
        #pragma unroll
        for (int n = 0; n < 2; ++n)
          acc[m][n] = __builtin_amdgcn_mfma_i32_16x16x64_i8(
              af[m], bf[n], acc[m][n], 0, 0, 0);
    }

    #pragma unroll
    for (int m = 0; m < 4; ++m) {
      int r0 = rbase + m * 16 + g4 * 4;
      float2 c0 = ic2[r0], c1 = ic2[r0 + 1], c2 = ic2[r0 + 2], c3 = ic2[r0 + 3];
      #pragma unroll
      for (int n = 0; n < 2; ++n) {
        int pxo = n * 16 + l15;
        const float* xq = xb + pxo;
        float*       oq = ob + pxo;
        size_t o0 = (size_t)r0 * HW;
        oq[o0]          = fmaf((float)acc[m][n].x, c0.x, c0.y) + xq[o0];
        oq[o0 + HW]     = fmaf((float)acc[m][n].y, c1.x, c1.y) + xq[o0 + HW];
        oq[o0 + 2 * HW] = fmaf((float)acc[m][n].z, c2.x, c2.y) + xq[o0 + 2 * HW];
        oq[o0 + 3 * HW] = fmaf((float)acc[m][n].w, c3.x, c3.y) + xq[o0 + 3 * HW];
      }
    }
  }
}

extern "C" void kernel_launch(void* const* d_in, const int* in_sizes, int n_in,
                              void* d_out, int out_size, void* d_ws, size_t ws_size,
                              hipStream_t stream) {
  const float* x  = (const float*)d_in[0];
  const float* w1 = (const float*)d_in[1];
  const float* w2 = (const float*)d_in[2];
  const float* g1 = (const float*)d_in[3];
  const float* b1 = (const float*)d_in[4];
  const float* m1 = (const float*)d_in[5];
  const float* v1 = (const float*)d_in[6];
  const float* g2 = (const float*)d_in[7];
  const float* b2 = (const float*)d_in[8];
  const float* m2 = (const float*)d_in[9];
  const float* v2 = (const float*)d_in[10];
  float* out = (float*)d_out;

  char*   w1b = (char*)d_ws;               // 196608 B
  char*   w2b = w1b + 196608;              // 196608 B
  float2* ic1 = (float2*)(w2b + 196608);   // 768 * 8 B
  float2* ic2 = ic1 + CMID;                // 256 * 8 B

  prep_kernel<<<1552, 64, 0, stream>>>(w1, w2, g1, b1, m1, v1,
                                       g2, b2, m2, v2, w1b, w2b, ic1, ic2);
  bnn_kernel<<<3136, 256, 0, stream>>>(x, w1b, w2b, ic1, ic2, out);
}

// Round 13
// 108.381 us; speedup vs baseline: 1.8293x; 1.8293x over previous
//
#include <hip/hip_runtime.h>

typedef unsigned long long u64;
typedef int i32x4 __attribute__((ext_vector_type(4)));

#define HW    3136      // 56*56 ; 3136 % 64 == 0 -> tiles never straddle images
#define CIN   256
#define CMID  768
#define EPSV  1e-5

// ---------------------------------------------------------------------------
// prep: weights -> i8 sign matrices in MFMA-FRAGMENT-TILED layout:
//   tile = 16 rows x 64 k; byte [tile*1024 + lane*16 + j] = sign of
//   w[row = tile_r*16 + (lane&15)][k = tile_k*64 + (lane>>4)*16 + j].
//   => kernel's A-fragment load is uniform-base + lane*16 (coalesced 1KB).
// BN folded to (inv, c) f32 pairs: y_bn = y*inv + c.
// ---------------------------------------------------------------------------
__global__ __launch_bounds__(64) void prep_kernel(
    const float* __restrict__ w1, const float* __restrict__ w2,
    const float* __restrict__ g1, const float* __restrict__ b1,
    const float* __restrict__ m1, const float* __restrict__ v1,
    const float* __restrict__ g2, const float* __restrict__ b2,
    const float* __restrict__ m2, const float* __restrict__ v2,
    char* __restrict__ w1t, char* __restrict__ w2t,
    float2* __restrict__ ic1, float2* __restrict__ ic2)
{
  int blk = blockIdx.x, lane = threadIdx.x;
  if (blk < 384) {                        // 192 W1 tiles + 192 W2 tiles
    const float* src;
    char* dst;
    int row, k0, ldk;
    if (blk < 192) {                      // W1: 48 row-tiles x 4 k-tiles
      int rt = blk >> 2, kt = blk & 3;
      row = rt * 16 + (lane & 15);
      k0  = kt * 64 + (lane >> 4) * 16;
      src = w1; ldk = 256; dst = w1t + (size_t)blk * 1024;
    } else {                              // W2: 16 row-tiles x 12 k-tiles
      int tid = blk - 192;
      int rt = tid / 12, kt = tid - rt * 12;
      row = rt * 16 + (lane & 15);
      k0  = kt * 64 + (lane >> 4) * 16;
      src = w2; ldk = 768; dst = w2t + (size_t)tid * 1024;
    }
    const float* sp = src + (size_t)row * ldk + k0;
    unsigned d[4];
    #pragma unroll
    for (int q = 0; q < 4; ++q) {
      unsigned dv = 0;
      #pragma unroll
      for (int j = 0; j < 4; ++j) {
        float v = sp[q * 4 + j];
        unsigned s = (v < 0.f) ? 0xFFu : (v > 0.f ? 1u : 0u);
        dv |= s << (8 * j);
      }
      d[q] = dv;
    }
    i32x4 vv; vv.x = (int)d[0]; vv.y = (int)d[1]; vv.z = (int)d[2]; vv.w = (int)d[3];
    *(i32x4*)(dst + lane * 16) = vv;
  } else {                                // BN constants (blocks 384..399)
    int i = (blk - 384) * 64 + lane;
    if (i < CMID) {
      double inv = (double)g1[i] / sqrt((double)v1[i] + EPSV);
      float2 o; o.x = (float)inv;
      o.y = (float)((double)b1[i] - (double)m1[i] * inv);
      ic1[i] = o;
    } else if (i < CMID + CIN) {
      int j = i - CMID;
      double inv = (double)g2[j] / sqrt((double)v2[j] + EPSV);
      float2 o; o.x = (float)inv;
      o.y = (float)((double)b2[j] - (double)m2[j] * inv);
      ic2[j] = o;
    }
  }
}

// ---------------------------------------------------------------------------
// main: R7 structure verbatim (1568 blocks x 4 waves, 64-px tile, both layers
// on MFMA, sBx/sY XOR-swizzled LDS) with ONE change: A-fragment loads use the
// fragment-tiled weight layout -> uniform base + lane*16, fully coalesced.
// ---------------------------------------------------------------------------
__global__ __launch_bounds__(256, 2) void bnn_kernel(
    const float* __restrict__ x,
    const char* __restrict__ w1t, const char* __restrict__ w2t,
    const float2* __restrict__ ic1, const float2* __restrict__ ic2,
    float* __restrict__ out)
{
  __shared__ __align__(16) char sBx[64 * 256];   // 16 KB
  __shared__ __align__(16) char sY[64 * 768];    // 48 KB  (total 64 KB)

  int t    = threadIdx.x;
  int w    = t >> 6;
  int lane = t & 63;
  int l15  = lane & 15;
  int g4   = lane >> 4;
  int swz  = l15 << 4;
  int lb   = lane << 4;                // byte offset of this lane's fragment

  int px0 = blockIdx.x * 64;           // 1568*64 == 100352 exactly
  int b   = px0 / HW;
  int hw0 = px0 - b * HW;
  const float* xb = x   + (size_t)b * (CIN * HW) + hw0;
  float*       ob = out + (size_t)b * (CIN * HW) + hw0;

  // ---- pack: thread packs px=lane, chans [64w,64w+64) -> i8 {-1,0,1} ----
  {
    const float* xp = xb + lane + (size_t)(w << 6) * HW;
    int rowbase = lane * 256 + (w << 6);
    int pswz    = (lane & 15) << 4;
    #pragma unroll
    for (int j = 0; j < 4; ++j) {      // 4 x b128 (16 chans each)
      unsigned d[4];
      #pragma unroll
      for (int q = 0; q < 4; ++q) {
        unsigned dv = 0;
        #pragma unroll
        for (int bb = 0; bb < 4; ++bb) {
          int c = j * 16 + q * 4 + bb;
          unsigned u = __float_as_uint(xp[(size_t)c * HW]);
          unsigned s = ((u + u) == 0u) ? 0u : (((int)u < 0) ? 0xFFu : 1u);
          dv |= s << (8 * bb);
        }
        d[q] = dv;
      }
      i32x4 v; v.x = (int)d[0]; v.y = (int)d[1]; v.z = (int)d[2]; v.w = (int)d[3];
      *(i32x4*)&sBx[(rowbase + j * 16) ^ pswz] = v;
    }
  }
  __syncthreads();

  // ---- hoist B-fragments (whole K=256) ----
  i32x4 bfa[4][4];                     // [ks][n]
  #pragma unroll
  for (int ks = 0; ks < 4; ++ks) {
    int k0 = ks * 64 + g4 * 16;
    #pragma unroll
    for (int n = 0; n < 4; ++n)
      bfa[ks][n] = *(const i32x4*)&sBx[((n * 16 + l15) * 256 + k0) ^ swz];
  }

  // ---- layer 1: 4 chunks of 48 rows; coalesced tiled-A loads ----
  #pragma unroll 1
  for (int ch = 0; ch < 4; ++ch) {
    int rt0 = w * 12 + ch * 3;         // row-tile index of m=0
    i32x4 acc[3][4];
    #pragma unroll
    for (int m = 0; m < 3; ++m)
      #pragma unroll
      for (int n = 0; n < 4; ++n) acc[m][n] = (i32x4)0;

    #pragma unroll
    for (int ks = 0; ks < 4; ++ks) {
      i32x4 af[3];
      #pragma unroll
      for (int m = 0; m < 3; ++m)
        af[m] = *(const i32x4*)&w1t[(size_t)((rt0 + m) * 4 + ks) * 1024 + lb];
      #pragma unroll
      for (int m = 0; m < 3; ++m)
        #pragma unroll
        for (int n = 0; n < 4; ++n)
          acc[m][n] = __builtin_amdgcn_mfma_i32_16x16x64_i8(
              af[m], bfa[ks][n], acc[m][n], 0, 0, 0);
    }

    // epilogue: BN-threshold -> i8 sign bytes into sY
    #pragma unroll
    for (int m = 0; m < 3; ++m) {
      int r0 = (rt0 + m) * 16 + g4 * 4;
      float2 c0 = ic1[r0], c1 = ic1[r0 + 1], c2 = ic1[r0 + 2], c3 = ic1[r0 + 3];
      #pragma unroll
      for (int n = 0; n < 4; ++n) {
        int px = n * 16 + l15;
        float y0 = fmaf((float)acc[m][n].x, c0.x, c0.y);
        float y1 = fmaf((float)acc[m][n].y, c1.x, c1.y);
        float y2 = fmaf((float)acc[m][n].z, c2.x, c2.y);
        float y3 = fmaf((float)acc[m][n].w, c3.x, c3.y);
        unsigned dv =
            (unsigned)(y0 < 0.f ? 0xFFu : (y0 > 0.f ? 1u : 0u))
          | ((unsigned)(y1 < 0.f ? 0xFFu : (y1 > 0.f ? 1u : 0u)) << 8)
          | ((unsigned)(y2 < 0.f ? 0xFFu : (y2 > 0.f ? 1u : 0u)) << 16)
          | ((unsigned)(y3 < 0.f ? 0xFFu : (y3 > 0.f ? 1u : 0u)) << 24);
        *(unsigned*)&sY[(px * 768 + r0) ^ swz] = dv;
      }
    }
  }
  __syncthreads();

  // ---- layer 2: wave rows [64w,+64), K=768; coalesced tiled-A loads ----
  {
    int rbase = w << 6;
    i32x4 acc[4][4];
    #pragma unroll
    for (int m = 0; m < 4; ++m)
      #pragma unroll
      for (int n = 0; n < 4; ++n) acc[m][n] = (i32x4)0;

    #pragma unroll 4
    for (int ks = 0; ks < 12; ++ks) {
      int k0 = ks * 64 + g4 * 16;
      i32x4 bf[4];
      #pragma unroll
      for (int n = 0; n < 4; ++n)
        bf[n] = *(const i32x4*)&sY[((n * 16 + l15) * 768 + k0) ^ swz];
      i32x4 af[4];
      #pragma unroll
      for (int m = 0; m < 4; ++m)
        af[m] = *(const i32x4*)&w2t[(size_t)((w * 4 + m) * 12 + ks) * 1024 + lb];
      #pragma unroll
      for (int m = 0; m < 4; ++m)
        #pragma unroll
        for (int n = 0; n < 4; ++n)
          acc[m][n] = __builtin_amdgcn_mfma_i32_16x16x64_i8(
              af[m], bf[n], acc[m][n], 0, 0, 0);
    }

    // epilogue: BN + residual + store
    #pragma unroll
    for (int m = 0; m < 4; ++m) {
      int r0 = rbase + m * 16 + g4 * 4;
      float2 c0 = ic2[r0], c1 = ic2[r0 + 1], c2 = ic2[r0 + 2], c3 = ic2[r0 + 3];
      #pragma unroll
      for (int n = 0; n < 4; ++n) {
        int pxo = n * 16 + l15;
        const float* xq = xb + pxo;
        float*       oq = ob + pxo;
        size_t o0 = (size_t)r0 * HW;
        oq[o0]          = fmaf((float)acc[m][n].x, c0.x, c0.y) + xq[o0];
        oq[o0 + HW]     = fmaf((float)acc[m][n].y, c1.x, c1.y) + xq[o0 + HW];
        oq[o0 + 2 * HW] = fmaf((float)acc[m][n].z, c2.x, c2.y) + xq[o0 + 2 * HW];
        oq[o0 + 3 * HW] = fmaf((float)acc[m][n].w, c3.x, c3.y) + xq[o0 + 3 * HW];
      }
    }
  }
}

extern "C" void kernel_launch(void* const* d_in, const int* in_sizes, int n_in,
                              void* d_out, int out_size, void* d_ws, size_t ws_size,
                              hipStream_t stream) {
  const float* x  = (const float*)d_in[0];
  const float* w1 = (const float*)d_in[1];
  const float* w2 = (const float*)d_in[2];
  const float* g1 = (const float*)d_in[3];
  const float* b1 = (const float*)d_in[4];
  const float* m1 = (const float*)d_in[5];
  const float* v1 = (const float*)d_in[6];
  const float* g2 = (const float*)d_in[7];
  const float* b2 = (const float*)d_in[8];
  const float* m2 = (const float*)d_in[9];
  const float* v2 = (const float*)d_in[10];
  float* out = (float*)d_out;

  char*   w1t = (char*)d_ws;               // 192 tiles * 1024 B = 196608 B
  char*   w2t = w1t + 196608;              // 192 tiles * 1024 B = 196608 B
  float2* ic1 = (float2*)(w2t + 196608);   // 768 * 8 B
  float2* ic2 = ic1 + CMID;                // 256 * 8 B

  prep_kernel<<<400, 64, 0, stream>>>(w1, w2, g1, b1, m1, v1,
                                      g2, b2, m2, v2, w1t, w2t, ic1, ic2);
  bnn_kernel<<<1568, 256, 0, stream>>>(x, w1t, w2t, ic1, ic2, out);
}